// Round 10
// baseline (482.875 us; speedup 1.0000x reference)
//
#include <hip/hip_runtime.h>
#include <hip/hip_bf16.h>
#include <cstdint>
#include <cstddef>

// BertMoE: B=4,S=2048,H=768,F=3072,E=8,K=2. tokens T=8192, pairs=16384.
#define T_TOK 8192
#define HDIM  768
#define FDIM  3072
#define NEXP  8

typedef __attribute__((ext_vector_type(8))) __bf16 bf16x8;
typedef __attribute__((ext_vector_type(4))) float  f32x4;

static __device__ __forceinline__ f32x4 mfma16(bf16x8 a, bf16x8 b, f32x4 c) {
  return __builtin_amdgcn_mfma_f32_16x16x32_bf16(a, b, c, 0, 0, 0);
}

static __device__ __forceinline__ unsigned short f2b(float f) {
  return __builtin_bit_cast(unsigned short, (__bf16)f);
}

// fast gelu: 0.5x(1+tanh(0.79788456(x+0.044715x^3))), max |err| ~3e-4 (R5/R6-validated)
static __device__ __forceinline__ float gelu_f(float x) {
  float x2 = x * x;
  float y = x * (0.7978845608f + 0.0356774081f * x2);
  float ay = __builtin_fabsf(y);
  float z = __builtin_amdgcn_exp2f(ay * -2.885390082f);   // exp(-2|y|)
  float t = (1.0f - z) * __builtin_amdgcn_rcpf(1.0f + z);
  t = __builtin_copysignf(t, y);
  return 0.5f * x * (1.0f + t);
}

// ---------------- workspace layout (bytes) ----------------
static constexpr size_t OFF_XB   = 0;                                        // T*H bf16
static constexpr size_t OFF_WIB  = OFF_XB  + (size_t)T_TOK * HDIM * 2;       // E*F*H bf16
static constexpr size_t OFF_WOB  = OFF_WIB + (size_t)NEXP * FDIM * HDIM * 2; // E*H*F bf16
static constexpr size_t OFF_HBUF = OFF_WOB + (size_t)NEXP * HDIM * FDIM * 2; // 2T*F bf16
static constexpr size_t OFF_META = OFF_HBUF + (size_t)2 * T_TOK * FDIM * 2;
static constexpr size_t OFF_TOKE = OFF_META + 256;
static constexpr size_t OFF_TOKW = OFF_TOKE + 65536;
static constexpr size_t OFF_PTOK = OFF_TOKW + 65536;
static constexpr size_t OFF_PW   = OFF_PTOK + 65536;
static constexpr size_t OFF_TILE = OFF_PW + 65536;    // tile_e[128], tile_mt[128], ntiles
// stage [16384][768] f32 = 50.33 MB: ALIASES xb+wib (dead once gemmA is done)
static constexpr size_t OFF_STAGE = 0;

// ---------------- fp32 -> bf16 convert ----------------
__global__ __launch_bounds__(256) void cvt_kernel(const float* __restrict__ s,
                                                  unsigned short* __restrict__ d, int n4) {
  int i = blockIdx.x * 256 + threadIdx.x;
  int stride = gridDim.x * 256;
  for (; i < n4; i += stride) {
    float4 v = ((const float4*)s)[i];
    ushort4 o;
    o.x = f2b(v.x); o.y = f2b(v.y); o.z = f2b(v.z); o.w = f2b(v.w);
    ((ushort4*)d)[i] = o;
  }
}

// ---------------- router: logits, top2, softmax; also emits xb (bf16 of x) ----------------
__global__ __launch_bounds__(256) void router_kernel(const float* __restrict__ x,
                                                     const float* __restrict__ Wr,
                                                     int* __restrict__ tok_e,
                                                     float* __restrict__ tok_w,
                                                     unsigned short* __restrict__ xb) {
  __shared__ float wr[NEXP * HDIM];
  int tid = threadIdx.x;
  for (int i = tid; i < NEXP * HDIM; i += 256) wr[i] = Wr[i];
  __syncthreads();
  int lane = tid & 63;
  int wv = tid >> 6;
  int t = blockIdx.x * 4 + wv;
  const float* xr = x + (size_t)t * HDIM;
  unsigned short* xbr = xb + (size_t)t * HDIM;
  float p[NEXP];
#pragma unroll
  for (int e = 0; e < NEXP; ++e) p[e] = 0.f;
  for (int j = 0; j < HDIM / 64; ++j) {
    float xv = xr[j * 64 + lane];
    xbr[j * 64 + lane] = f2b(xv);
#pragma unroll
    for (int e = 0; e < NEXP; ++e) p[e] += xv * wr[e * HDIM + j * 64 + lane];
  }
#pragma unroll
  for (int e = 0; e < NEXP; ++e) {
    float v = p[e];
    for (int off = 32; off; off >>= 1) v += __shfl_xor(v, off);
    p[e] = v;
  }
  if (lane == 0) {
    float v0 = -1e30f, v1 = -1e30f; int i0 = 0, i1 = 0;
#pragma unroll
    for (int e = 0; e < NEXP; ++e) {
      float v = p[e];
      if (v > v0) { v1 = v0; i1 = i0; v0 = v; i0 = e; }
      else if (v > v1) { v1 = v; i1 = e; }
    }
    float ew = expf(v1 - v0);
    float w0 = 1.0f / (1.0f + ew);
    float w1 = ew * w0;
    tok_e[t * 2 + 0] = i0; tok_w[t * 2 + 0] = w0;
    tok_e[t * 2 + 1] = i1; tok_w[t * 2 + 1] = w1;
  }
}

// ---------------- count / scan+tiles / scatter ----------------
__global__ __launch_bounds__(256) void count_kernel(const int* __restrict__ tok_e,
                                                    int* __restrict__ counts) {
  __shared__ int h[NEXP];
  int tid = threadIdx.x;
  if (tid < NEXP) h[tid] = 0;
  __syncthreads();
  int i = blockIdx.x * 256 + tid;
  atomicAdd(&h[tok_e[i]], 1);
  __syncthreads();
  if (tid < NEXP && h[tid] > 0) atomicAdd(&counts[tid], h[tid]);
}

__global__ void scan_build_kernel(const int* __restrict__ counts, int* __restrict__ basep,
                                  int* __restrict__ tile_e, int* __restrict__ tile_mt,
                                  int* __restrict__ ntiles) {
  if (threadIdx.x != 0 || blockIdx.x != 0) return;
  int s = 0;
  for (int e = 0; e < NEXP; ++e) { basep[e] = s; s += counts[e]; }
  int n = 0;
  for (int e = 0; e < NEXP; ++e) {
    int nmt = (counts[e] + 255) >> 8;
    for (int m = 0; m < nmt; ++m) { tile_e[n] = e; tile_mt[n] = m; ++n; }
  }
  ntiles[0] = n;
}

__global__ __launch_bounds__(256) void scatter_kernel(const int* __restrict__ tok_e,
                                                      const float* __restrict__ tok_w,
                                                      const int* __restrict__ base,
                                                      int* __restrict__ cursor,
                                                      int* __restrict__ pair_tok,
                                                      float* __restrict__ pair_w) {
  __shared__ int h[NEXP], bstart[NEXP];
  int tid = threadIdx.x;
  if (tid < NEXP) h[tid] = 0;
  __syncthreads();
  int i = blockIdx.x * 256 + tid;
  int e = tok_e[i];
  int r = atomicAdd(&h[e], 1);
  __syncthreads();
  if (tid < NEXP) bstart[tid] = (h[tid] > 0) ? atomicAdd(&cursor[tid], h[tid]) : 0;
  __syncthreads();
  int pos = base[e] + bstart[e] + r;
  pair_tok[pos] = i;          // packed (tok<<1)|slot
  pair_w[pos] = tok_w[i];
}

// ---------------- grouped GEMM, 256x256 tile, 8-phase / 2 K-tiles (m201 port) ----------------
// MODE 0: H = gelu(X * Wi^T + bi) -> hbuf (bf16), A gathered, K=768  (NT=12, 6 iters)
// MODE 1: stage = (H * Wo^T + bo)*w (f32),      A contiguous, K=3072 (NT=48, 24 iters)
// Quadrant-cooperative: per phase all 8 waves compute ONE 128x128 C-quadrant
// (wave slice 64x32 = 16 MFMA), reading only ONE LDS A-half or B-half.
// Stage 1 half-tile (16KB, 2 gloads) per phase; counted vmcnt(6)/vmcnt(8) waits
// give every staged half 4-6 phases of landing slack. Never drains mid-loop.
template <int MODE>
__global__ __launch_bounds__(512, 2) void moe_gemm(
    const unsigned short* __restrict__ abase,
    const unsigned short* __restrict__ wbase,
    const float* __restrict__ bias,
    const int* __restrict__ counts, const int* __restrict__ base,
    const int* __restrict__ pair_tok, const float* __restrict__ pair_w,
    const int* __restrict__ tile_e, const int* __restrict__ tile_mt,
    const int* __restrict__ ntiles,
    unsigned short* __restrict__ hbuf, float* __restrict__ stage) {
  constexpr int K   = MODE ? FDIM : HDIM;
  constexpr int N   = MODE ? HDIM : FDIM;
  constexpr int NT  = K / 64;           // even
  constexpr int NTC = N / 256;

  // ---- work decode: nt-major, mt-inner (R8 best)
  const int xcd = blockIdx.x & 7;
  const int slot = blockIdx.x >> 3;
  const int mtl = slot % 9;
  const int nt = slot / 9;
  const int ntl = ntiles[0];
  const int q = ntl >> 3, r = ntl & 7;
  const int cnt = q + (xcd < r ? 1 : 0);
  if (mtl >= cnt) return;
  const int gt = xcd * q + (xcd < r ? xcd : r) + mtl;
  const int e = tile_e[gt];
  const int mt = tile_mt[gt];
  const int ne = counts[e];
  const int pb = base[e];

  extern __shared__ char smem[];        // buf0 @0 (A 32K | B 32K), buf1 @65536

  const int tid = threadIdx.x;
  const int lane = tid & 63;
  const int wv = tid >> 6;
  const int wlo = wv & 1;               // 64-row half within quadrant
  const int whi = wv >> 1;              // 0..3: 32-col band within quadrant
  const int l15 = lane & 15;
  const int lkb = (lane >> 4) * 16;

  // ---- staging source addresses (pre-swizzled global so LDS lands swizzled)
  const int crow = tid >> 3;
  const int ck = tid & 7;
  const int swz = (ck ^ (crow & 7)) * 16;
  const char* aS[4]; const char* bS[4];
#pragma unroll
  for (int i = 0; i < 4; ++i) {
    int gr = mt * 256 + i * 64 + crow; if (gr > ne - 1) gr = ne - 1;
    if constexpr (MODE == 0) {
      int tok = pair_tok[pb + gr] >> 1;
      aS[i] = (const char*)abase + (size_t)tok * (HDIM * 2) + swz;
    } else {
      aS[i] = (const char*)abase + (size_t)(pb + gr) * (FDIM * 2) + swz;
    }
    int br = nt * 256 + i * 64 + crow;
    bS[i] = (const char*)wbase + ((size_t)e * N * K + (size_t)br * K) * 2 + swz;
  }

  auto STAGE = [&](int c, int t) {      // chunk c (0-3: A 64-row blocks, 4-7: B), tile t
    if (t < NT) {
      const char* src = (c < 4 ? aS[c] : bS[c - 4]) + t * 128;
      char* dst = smem + (size_t)((t & 1) * 65536 + c * 8192 + tid * 16);
      __builtin_amdgcn_global_load_lds(
          (const __attribute__((address_space(1))) void*)src,
          (__attribute__((address_space(3))) void*)dst, 16, 0, 0);
    }
  };
  // half h: 0=A0(chunks 0,1) 1=A1(2,3) 2=B0(4,5) 3=B1(6,7)
  auto SH = [&](int h, int t) { STAGE(2 * h, t); STAGE(2 * h + 1, t); };

  bf16x8 aR[8], bR0[4], bR1[4];
  f32x4 acc[4][4][2];                   // [q=qm*2+qn][mf][nf]
#pragma unroll
  for (int qi = 0; qi < 4; ++qi)
#pragma unroll
    for (int mf = 0; mf < 4; ++mf)
#pragma unroll
      for (int nf = 0; nf < 2; ++nf) acc[qi][mf][nf] = (f32x4){0.f, 0.f, 0.f, 0.f};

  auto RA = [&](int cb, int qm) {       // 8 ds_read_b128
#pragma unroll
    for (int mf = 0; mf < 4; ++mf)
#pragma unroll
      for (int kh = 0; kh < 2; ++kh) {
        int lr = qm * 128 + wlo * 64 + mf * 16 + l15;
        aR[mf * 2 + kh] =
            *(const bf16x8*)(smem + cb + lr * 128 + ((kh * 64 + lkb) ^ ((lr & 7) << 4)));
      }
  };
  auto RB = [&](int cb, int qn, bf16x8* bR) {   // 4 ds_read_b128
#pragma unroll
    for (int nf = 0; nf < 2; ++nf)
#pragma unroll
      for (int kh = 0; kh < 2; ++kh) {
        int lb = qn * 128 + whi * 32 + nf * 16 + l15;
        bR[nf * 2 + kh] =
            *(const bf16x8*)(smem + cb + 32768 + lb * 128 + ((kh * 64 + lkb) ^ ((lb & 7) << 4)));
      }
  };
  auto MQ = [&](int qi, const bf16x8* bR) {     // 16 MFMA
#pragma unroll
    for (int mf = 0; mf < 4; ++mf)
#pragma unroll
      for (int nf = 0; nf < 2; ++nf)
#pragma unroll
        for (int kh = 0; kh < 2; ++kh)
          acc[qi][mf][nf] = mfma16(aR[mf * 2 + kh], bR[nf * 2 + kh], acc[qi][mf][nf]);
  };

#define BAR()   __builtin_amdgcn_s_barrier()
#define LGKM0() asm volatile("s_waitcnt lgkmcnt(0)" ::: "memory"); \
                __builtin_amdgcn_sched_barrier(0)
#define P1()    __builtin_amdgcn_s_setprio(1)
#define P0()    __builtin_amdgcn_s_setprio(0)

  // ---- prologue: A0,B1,B0,A1 of tile0; A0,B1 of tile1 (12 issues)
  SH(0, 0); SH(3, 0); SH(2, 0); SH(1, 0); SH(0, 1); SH(3, 1);
  asm volatile("s_waitcnt vmcnt(6)" ::: "memory");
  BAR();

  for (int it = 0; it < NT / 2; ++it) {
    const int u = 2 * it, v = u + 1;
    const bool last = (it == NT / 2 - 1);
    // ph0: Q00(u); stage B0(v)
    RA(0, 0); RB(0, 0, bR0); SH(2, v);
    BAR(); LGKM0(); P1(); MQ(0, bR0); P0(); BAR();
    // ph1: Q01(u); stage A1(v)
    RB(0, 1, bR1); SH(1, v);
    BAR(); LGKM0(); P1(); MQ(1, bR1); P0();
    asm volatile("s_waitcnt vmcnt(8)" ::: "memory");
    BAR();
    // ph2: Q11(u); stage A0(u+2)
    RA(0, 1); SH(0, u + 2);
    BAR(); LGKM0(); P1(); MQ(3, bR1); P0(); BAR();
    // ph3: Q10(u); stage B1(u+2)
    SH(3, u + 2);
    BAR(); P1(); MQ(2, bR0); P0();
    if (!last) asm volatile("s_waitcnt vmcnt(6)" ::: "memory");
    else       asm volatile("s_waitcnt vmcnt(2)" ::: "memory");
    BAR();
    // ph4: Q00(v); stage B0(u+2)
    RA(65536, 0); RB(65536, 0, bR0); SH(2, u + 2);
    BAR(); LGKM0(); P1(); MQ(0, bR0); P0(); BAR();
    // ph5: Q01(v); stage A1(u+2)
    RB(65536, 1, bR1); SH(1, u + 2);
    BAR(); LGKM0(); P1(); MQ(1, bR1); P0();
    if (!last) asm volatile("s_waitcnt vmcnt(8)" ::: "memory");
    else       asm volatile("s_waitcnt vmcnt(0)" ::: "memory");
    BAR();
    // ph6: Q11(v); stage A0(v+2)
    RA(65536, 1); SH(0, v + 2);
    BAR(); LGKM0(); P1(); MQ(3, bR1); P0(); BAR();
    // ph7: Q10(v); stage B1(v+2)
    SH(3, v + 2);
    BAR(); P1(); MQ(2, bR0); P0();
    asm volatile("s_waitcnt vmcnt(6)" ::: "memory");
    BAR();
  }

  // ---- epilogue: row = mt*256 + qm*128 + wlo*64 + mf*16 + (lane>>4)*4 + rr
  //               col = nt*256 + qn*128 + whi*32 + nf*16 + l15
#pragma unroll
  for (int qi = 0; qi < 4; ++qi) {
    const int qm = qi >> 1, qn = qi & 1;
    if constexpr (MODE == 0) {
      const float* be = bias + (size_t)e * FDIM;
      float bv[2];
#pragma unroll
      for (int nf = 0; nf < 2; ++nf)
        bv[nf] = be[nt * 256 + qn * 128 + whi * 32 + nf * 16 + l15];
#pragma unroll
      for (int mf = 0; mf < 4; ++mf)
#pragma unroll
        for (int rr = 0; rr < 4; ++rr) {
          int row = mt * 256 + qm * 128 + wlo * 64 + mf * 16 + (lane >> 4) * 4 + rr;
          if (row < ne) {
            unsigned short* hr = hbuf + (size_t)(pb + row) * FDIM +
                                 nt * 256 + qn * 128 + whi * 32 + l15;
#pragma unroll
            for (int nf = 0; nf < 2; ++nf)
              hr[nf * 16] = f2b(gelu_f(acc[qi][mf][nf][rr] + bv[nf]));
          }
        }
    } else {
      const float* be = bias + (size_t)e * HDIM;
      float bv[2];
#pragma unroll
      for (int nf = 0; nf < 2; ++nf)
        bv[nf] = be[nt * 256 + qn * 128 + whi * 32 + nf * 16 + l15];
#pragma unroll
      for (int mf = 0; mf < 4; ++mf)
#pragma unroll
        for (int rr = 0; rr < 4; ++rr) {
          int row = mt * 256 + qm * 128 + wlo * 64 + mf * 16 + (lane >> 4) * 4 + rr;
          if (row < ne) {
            int p = pb + row;
            int ts = pair_tok[p];        // (tok<<1)|slot in [0,16384)
            float w = pair_w[p];
            float* sr = stage + (size_t)ts * HDIM + nt * 256 + qn * 128 + whi * 32 + l15;
#pragma unroll
            for (int nf = 0; nf < 2; ++nf)
              sr[nf * 16] = (acc[qi][mf][nf][rr] + bv[nf]) * w;
          }
        }
    }
  }
#undef BAR
#undef LGKM0
#undef P1
#undef P0
}

// ---------------- combine: out[t] = stage[2t] + stage[2t+1] ----------------
__global__ __launch_bounds__(256) void combine_kernel(const float* __restrict__ stage,
                                                      float* __restrict__ out) {
  const int n4 = T_TOK * HDIM / 4;
  int i = blockIdx.x * 256 + threadIdx.x;
  int stride = gridDim.x * 256;
  const float4* s = (const float4*)stage;
  float4* o = (float4*)out;
  for (; i < n4; i += stride) {
    int t = i / (HDIM / 4);
    int h = i - t * (HDIM / 4);
    float4 a = s[(size_t)t * (HDIM / 2) + h];
    float4 b = s[(size_t)t * (HDIM / 2) + (HDIM / 4) + h];
    float4 rr; rr.x = a.x + b.x; rr.y = a.y + b.y; rr.z = a.z + b.z; rr.w = a.w + b.w;
    o[i] = rr;
  }
}

extern "C" void kernel_launch(void* const* d_in, const int* in_sizes, int n_in,
                              void* d_out, int out_size, void* d_ws, size_t ws_size,
                              hipStream_t stream) {
  const float* x  = (const float*)d_in[0];
  const float* Wr = (const float*)d_in[1];
  const float* Wi = (const float*)d_in[2];
  const float* bi = (const float*)d_in[3];
  const float* Wo = (const float*)d_in[4];
  const float* bo = (const float*)d_in[5];
  float* out = (float*)d_out;
  char* ws = (char*)d_ws;

  unsigned short* xb   = (unsigned short*)(ws + OFF_XB);
  unsigned short* wib  = (unsigned short*)(ws + OFF_WIB);
  unsigned short* wob  = (unsigned short*)(ws + OFF_WOB);
  unsigned short* hbuf = (unsigned short*)(ws + OFF_HBUF);
  int*   counts   = (int*)(ws + OFF_META);
  int*   basep    = (int*)(ws + OFF_META + 64);
  int*   cursor   = (int*)(ws + OFF_META + 128);
  int*   tok_e    = (int*)(ws + OFF_TOKE);
  float* tok_w    = (float*)(ws + OFF_TOKW);
  int*   pair_tok = (int*)(ws + OFF_PTOK);
  float* pair_w   = (float*)(ws + OFF_PW);
  int*   tile_e   = (int*)(ws + OFF_TILE);
  int*   tile_mt  = (int*)(ws + OFF_TILE + 512);
  int*   ntiles   = (int*)(ws + OFF_TILE + 1024);
  float* stage    = (float*)(ws + OFF_STAGE);

  hipFuncSetAttribute((const void*)&moe_gemm<0>,
                      hipFuncAttributeMaxDynamicSharedMemorySize, 131072);
  hipFuncSetAttribute((const void*)&moe_gemm<1>,
                      hipFuncAttributeMaxDynamicSharedMemorySize, 131072);

  hipMemsetAsync(ws + OFF_META, 0, 256, stream);

  router_kernel<<<T_TOK / 4, 256, 0, stream>>>(x, Wr, tok_e, tok_w, xb);
  cvt_kernel<<<2048, 256, 0, stream>>>(Wi, wib, NEXP * FDIM * HDIM / 4);
  cvt_kernel<<<2048, 256, 0, stream>>>(Wo, wob, NEXP * HDIM * FDIM / 4);

  count_kernel<<<64, 256, 0, stream>>>(tok_e, counts);
  scan_build_kernel<<<1, 64, 0, stream>>>(counts, basep, tile_e, tile_mt, ntiles);
  scatter_kernel<<<64, 256, 0, stream>>>(tok_e, tok_w, basep, cursor, pair_tok, pair_w);

  // grids: 8 XCDs x 9 mt-slots x NTC; nt-major/mt-inner decode inside (R8 best)
  moe_gemm<0><<<8 * 9 * (FDIM / 256), 512, 131072, stream>>>(
      xb, wib, bi, counts, basep, pair_tok, pair_w, tile_e, tile_mt, ntiles, hbuf, nullptr);
  moe_gemm<1><<<8 * 9 * (HDIM / 256), 512, 131072, stream>>>(
      hbuf, wob, bo, counts, basep, pair_tok, pair_w, tile_e, tile_mt, ntiles, nullptr, stage);

  combine_kernel<<<2048, 256, 0, stream>>>(stage, out);
}

// Round 11
// 295.061 us; speedup vs baseline: 1.6365x; 1.6365x over previous
//
#include <hip/hip_runtime.h>
#include <hip/hip_bf16.h>
#include <cstdint>
#include <cstddef>

// BertMoE: B=4,S=2048,H=768,F=3072,E=8,K=2. tokens T=8192, pairs=16384.
#define T_TOK 8192
#define HDIM  768
#define FDIM  3072
#define NEXP  8

typedef __attribute__((ext_vector_type(8))) __bf16 bf16x8;
typedef __attribute__((ext_vector_type(4))) float  f32x4;

static __device__ __forceinline__ f32x4 mfma16(bf16x8 a, bf16x8 b, f32x4 c) {
  return __builtin_amdgcn_mfma_f32_16x16x32_bf16(a, b, c, 0, 0, 0);
}

static __device__ __forceinline__ unsigned short f2b(float f) {
  return __builtin_bit_cast(unsigned short, (__bf16)f);
}

// fast gelu: 0.5x(1+tanh(0.79788456(x+0.044715x^3))), max |err| ~3e-4 (R5/R6-validated)
static __device__ __forceinline__ float gelu_f(float x) {
  float x2 = x * x;
  float y = x * (0.7978845608f + 0.0356774081f * x2);
  float ay = __builtin_fabsf(y);
  float z = __builtin_amdgcn_exp2f(ay * -2.885390082f);   // exp(-2|y|)
  float t = (1.0f - z) * __builtin_amdgcn_rcpf(1.0f + z);
  t = __builtin_copysignf(t, y);
  return 0.5f * x * (1.0f + t);
}

// ---------------- workspace layout (bytes) ----------------
static constexpr size_t OFF_XB   = 0;                                        // T*H bf16
static constexpr size_t OFF_WIB  = OFF_XB  + (size_t)T_TOK * HDIM * 2;       // E*F*H bf16
static constexpr size_t OFF_WOB  = OFF_WIB + (size_t)NEXP * FDIM * HDIM * 2; // E*H*F bf16
static constexpr size_t OFF_HBUF = OFF_WOB + (size_t)NEXP * HDIM * FDIM * 2; // 2T*F bf16
static constexpr size_t OFF_META = OFF_HBUF + (size_t)2 * T_TOK * FDIM * 2;
static constexpr size_t OFF_TOKE = OFF_META + 256;
static constexpr size_t OFF_TOKW = OFF_TOKE + 65536;
static constexpr size_t OFF_PTOK = OFF_TOKW + 65536;
static constexpr size_t OFF_PW   = OFF_PTOK + 65536;
static constexpr size_t OFF_TILE = OFF_PW + 65536;    // tile_e[128], tile_mt[128], ntiles
// stage [16384][768] f32 = 50.33 MB: ALIASES xb+wib (dead once gemmA is done)
static constexpr size_t OFF_STAGE = 0;

// ---------------- fp32 -> bf16 convert ----------------
__global__ __launch_bounds__(256) void cvt_kernel(const float* __restrict__ s,
                                                  unsigned short* __restrict__ d, int n4) {
  int i = blockIdx.x * 256 + threadIdx.x;
  int stride = gridDim.x * 256;
  for (; i < n4; i += stride) {
    float4 v = ((const float4*)s)[i];
    ushort4 o;
    o.x = f2b(v.x); o.y = f2b(v.y); o.z = f2b(v.z); o.w = f2b(v.w);
    ((ushort4*)d)[i] = o;
  }
}

// ---------------- router: logits, top2, softmax; also emits xb (bf16 of x) ----------------
__global__ __launch_bounds__(256) void router_kernel(const float* __restrict__ x,
                                                     const float* __restrict__ Wr,
                                                     int* __restrict__ tok_e,
                                                     float* __restrict__ tok_w,
                                                     unsigned short* __restrict__ xb) {
  __shared__ float wr[NEXP * HDIM];
  int tid = threadIdx.x;
  for (int i = tid; i < NEXP * HDIM; i += 256) wr[i] = Wr[i];
  __syncthreads();
  int lane = tid & 63;
  int wv = tid >> 6;
  int t = blockIdx.x * 4 + wv;
  const float* xr = x + (size_t)t * HDIM;
  unsigned short* xbr = xb + (size_t)t * HDIM;
  float p[NEXP];
#pragma unroll
  for (int e = 0; e < NEXP; ++e) p[e] = 0.f;
  for (int j = 0; j < HDIM / 64; ++j) {
    float xv = xr[j * 64 + lane];
    xbr[j * 64 + lane] = f2b(xv);
#pragma unroll
    for (int e = 0; e < NEXP; ++e) p[e] += xv * wr[e * HDIM + j * 64 + lane];
  }
#pragma unroll
  for (int e = 0; e < NEXP; ++e) {
    float v = p[e];
    for (int off = 32; off; off >>= 1) v += __shfl_xor(v, off);
    p[e] = v;
  }
  if (lane == 0) {
    float v0 = -1e30f, v1 = -1e30f; int i0 = 0, i1 = 0;
#pragma unroll
    for (int e = 0; e < NEXP; ++e) {
      float v = p[e];
      if (v > v0) { v1 = v0; i1 = i0; v0 = v; i0 = e; }
      else if (v > v1) { v1 = v; i1 = e; }
    }
    float ew = expf(v1 - v0);
    float w0 = 1.0f / (1.0f + ew);
    float w1 = ew * w0;
    tok_e[t * 2 + 0] = i0; tok_w[t * 2 + 0] = w0;
    tok_e[t * 2 + 1] = i1; tok_w[t * 2 + 1] = w1;
  }
}

// ---------------- count / scan+tiles / scatter ----------------
__global__ __launch_bounds__(256) void count_kernel(const int* __restrict__ tok_e,
                                                    int* __restrict__ counts) {
  __shared__ int h[NEXP];
  int tid = threadIdx.x;
  if (tid < NEXP) h[tid] = 0;
  __syncthreads();
  int i = blockIdx.x * 256 + tid;
  atomicAdd(&h[tok_e[i]], 1);
  __syncthreads();
  if (tid < NEXP && h[tid] > 0) atomicAdd(&counts[tid], h[tid]);
}

__global__ void scan_build_kernel(const int* __restrict__ counts, int* __restrict__ basep,
                                  int* __restrict__ tile_e, int* __restrict__ tile_mt,
                                  int* __restrict__ ntiles) {
  if (threadIdx.x != 0 || blockIdx.x != 0) return;
  int s = 0;
  for (int e = 0; e < NEXP; ++e) { basep[e] = s; s += counts[e]; }
  int n = 0;
  for (int e = 0; e < NEXP; ++e) {
    int nmt = (counts[e] + 255) >> 8;
    for (int m = 0; m < nmt; ++m) { tile_e[n] = e; tile_mt[n] = m; ++n; }
  }
  ntiles[0] = n;
}

__global__ __launch_bounds__(256) void scatter_kernel(const int* __restrict__ tok_e,
                                                      const float* __restrict__ tok_w,
                                                      const int* __restrict__ base,
                                                      int* __restrict__ cursor,
                                                      int* __restrict__ pair_tok,
                                                      float* __restrict__ pair_w) {
  __shared__ int h[NEXP], bstart[NEXP];
  int tid = threadIdx.x;
  if (tid < NEXP) h[tid] = 0;
  __syncthreads();
  int i = blockIdx.x * 256 + tid;
  int e = tok_e[i];
  int r = atomicAdd(&h[e], 1);
  __syncthreads();
  if (tid < NEXP) bstart[tid] = (h[tid] > 0) ? atomicAdd(&cursor[tid], h[tid]) : 0;
  __syncthreads();
  int pos = base[e] + bstart[e] + r;
  pair_tok[pos] = i;          // packed (tok<<1)|slot
  pair_w[pos] = tok_w[i];
}

// ---------------- grouped GEMM, 256x256 tile, BK=64, 8 waves ----------------
// MODE 0: H = gelu(X * Wi^T + bi) -> hbuf (bf16), A gathered via pair_tok, K=768,  NTC=12
// MODE 1: stage = (H * Wo^T + bo) * w      (f32), A contiguous (hbuf),    K=3072, NTC=3
//
// SINGLE-BUFFERED 64 KB LDS -> 2 blocks/CU co-resident (VGPR 120 fits 16 waves/CU).
// Inter-block TLP covers the per-K-tile vmcnt(0) drain (m114/m97 mechanism) that a
// 1-block/CU 128 KB double-buffer left fully exposed (R2-R8 all ~134 us).
// Loop: read frags -> lgkm0 -> barrier -> STAGE(t+1, same buf) -> MFMA -> vmcnt0 -> barrier.
template <int MODE>
__global__ __launch_bounds__(512, 2) void moe_gemm(
    const unsigned short* __restrict__ abase,
    const unsigned short* __restrict__ wbase,
    const float* __restrict__ bias,
    const int* __restrict__ counts, const int* __restrict__ base,
    const int* __restrict__ pair_tok, const float* __restrict__ pair_w,
    const int* __restrict__ tile_e, const int* __restrict__ tile_mt,
    const int* __restrict__ ntiles,
    unsigned short* __restrict__ hbuf, float* __restrict__ stage) {
  constexpr int K   = MODE ? FDIM : HDIM;
  constexpr int N   = MODE ? HDIM : FDIM;
  constexpr int NT  = K / 64;
  constexpr int NTC = N / 256;

  // ---- work decode: nt-major, mt-inner (R8 best)
  const int xcd = blockIdx.x & 7;
  const int slot = blockIdx.x >> 3;
  const int mtl = slot % 9;
  const int nt = slot / 9;
  const int ntl = ntiles[0];
  const int q = ntl >> 3, r = ntl & 7;
  const int cnt = q + (xcd < r ? 1 : 0);
  if (mtl >= cnt) return;
  const int gt = xcd * q + (xcd < r ? xcd : r) + mtl;
  const int e = tile_e[gt];
  const int mt = tile_mt[gt];
  const int ne = counts[e];
  const int pb = base[e];

  extern __shared__ char smem[];   // single buffer: A 32KB | B 32KB = 64 KB

  const int tid = threadIdx.x;
  const int lane = tid & 63;
  const int wv = tid >> 6;
  const int wm = wv >> 2;
  const int wn = wv & 3;
  const int l15 = lane & 15;
  const int lkb = (lane >> 4) * 16;

  // ---- staging source addresses (pre-swizzled global so LDS lands swizzled)
  const int crow = tid >> 3;
  const int ck = tid & 7;
  const int swz = (ck ^ (crow & 7)) * 16;
  const char* aS[4]; const char* bS[4];
#pragma unroll
  for (int i = 0; i < 4; ++i) {
    int gr = mt * 256 + i * 64 + crow; if (gr > ne - 1) gr = ne - 1;
    if constexpr (MODE == 0) {
      int tok = pair_tok[pb + gr] >> 1;
      aS[i] = (const char*)abase + (size_t)tok * (HDIM * 2) + swz;
    } else {
      aS[i] = (const char*)abase + (size_t)(pb + gr) * (FDIM * 2) + swz;
    }
    int br = nt * 256 + i * 64 + crow;
    bS[i] = (const char*)wbase + ((size_t)e * N * K + (size_t)br * K) * 2 + swz;
  }

  auto STAGE = [&](int t) {   // full 64KB tile: chunks 0-3 A, 4-7 B
    if (t < NT) {
#pragma unroll
      for (int c = 0; c < 8; ++c) {
        const char* src = (c < 4 ? aS[c] : bS[c - 4]) + t * 128;
        char* dst = smem + (size_t)(c * 8192 + tid * 16);
        __builtin_amdgcn_global_load_lds(
            (const __attribute__((address_space(1))) void*)src,
            (__attribute__((address_space(3))) void*)dst, 16, 0, 0);
      }
    }
  };

  bf16x8 aR[8], bR[8];
  f32x4 acc[8][4];
#pragma unroll
  for (int mi = 0; mi < 8; ++mi)
#pragma unroll
    for (int ni = 0; ni < 4; ++ni) acc[mi][ni] = (f32x4){0.f, 0.f, 0.f, 0.f};

  // ---- prologue: tile0
  STAGE(0);
  asm volatile("s_waitcnt vmcnt(0)" ::: "memory");
  __builtin_amdgcn_s_barrier();

  for (int t = 0; t < NT; ++t) {
    // read all fragments for this K-tile (per wave: 8 A + 8 B ds_read_b128)
#pragma unroll
    for (int mi = 0; mi < 8; ++mi)
#pragma unroll
      for (int k2 = 0; k2 < 2; ++k2) {
        int lr = wm * 128 + mi * 16 + l15;
        if (k2 == 0 || (mi & 1) == (mi & 1)) {}  // no-op
        aR[(mi & 3) * 2 + k2] = aR[(mi & 3) * 2 + k2];  // placeholder avoided below
      }
    // (explicit reads, grouped: 4 m-frags x 2 k-halves for each 64-row half)
    bf16x8 a0[8], b0[8];
#pragma unroll
    for (int m2 = 0; m2 < 4; ++m2)
#pragma unroll
      for (int k2 = 0; k2 < 2; ++k2) {
        int lr0 = wm * 128 + m2 * 16 + l15;
        int lr1 = wm * 128 + 64 + m2 * 16 + l15;
        a0[m2 * 2 + k2] =
            *(const bf16x8*)(smem + lr0 * 128 + ((k2 * 64 + lkb) ^ ((lr0 & 7) << 4)));
        aR[m2 * 2 + k2] =
            *(const bf16x8*)(smem + lr1 * 128 + ((k2 * 64 + lkb) ^ ((lr1 & 7) << 4)));
      }
#pragma unroll
    for (int n2 = 0; n2 < 4; ++n2)
#pragma unroll
      for (int k2 = 0; k2 < 2; ++k2) {
        int lb = wn * 64 + n2 * 16 + l15;
        b0[n2 * 2 + k2] =
            *(const bf16x8*)(smem + 32768 + lb * 128 + ((k2 * 64 + lkb) ^ ((lb & 7) << 4)));
      }
    asm volatile("s_waitcnt lgkmcnt(0)" ::: "memory");
    __builtin_amdgcn_sched_barrier(0);
    __builtin_amdgcn_s_barrier();           // all waves' reads retired -> buffer free
    STAGE(t + 1);                           // issue next tile into same buffer
    __builtin_amdgcn_sched_barrier(0);
    __builtin_amdgcn_s_setprio(1);
#pragma unroll
    for (int m2 = 0; m2 < 4; ++m2)
#pragma unroll
      for (int n2 = 0; n2 < 4; ++n2)
#pragma unroll
        for (int k2 = 0; k2 < 2; ++k2) {
          acc[m2][n2]     = mfma16(a0[m2 * 2 + k2], b0[n2 * 2 + k2], acc[m2][n2]);
          acc[4 + m2][n2] = mfma16(aR[m2 * 2 + k2], b0[n2 * 2 + k2], acc[4 + m2][n2]);
        }
    __builtin_amdgcn_s_setprio(0);
    __builtin_amdgcn_sched_barrier(0);
    asm volatile("s_waitcnt vmcnt(0)" ::: "memory");
    __builtin_amdgcn_s_barrier();
  }

  // ---- epilogue: row = mt*256 + wm*128 + (mi>=4?64:0) + (mi&3)*16 + (lane>>4)*4 + rr
  //               col = nt*256 + wn*64 + ni*16 + l15
  if constexpr (MODE == 0) {
    const float* be = bias + (size_t)e * FDIM;
    float bv[4];
#pragma unroll
    for (int ni = 0; ni < 4; ++ni) bv[ni] = be[nt * 256 + wn * 64 + ni * 16 + l15];
#pragma unroll
    for (int mi = 0; mi < 8; ++mi)
#pragma unroll
      for (int rr = 0; rr < 4; ++rr) {
        int row = mt * 256 + wm * 128 + (mi >> 2) * 64 + (mi & 3) * 16 + (lane >> 4) * 4 + rr;
        if (row < ne) {
          unsigned short* hr = hbuf + (size_t)(pb + row) * FDIM + nt * 256 + wn * 64 + l15;
#pragma unroll
          for (int ni = 0; ni < 4; ++ni)
            hr[ni * 16] = f2b(gelu_f(acc[(mi >> 2) * 4 + (mi & 3)][ni][rr] + bv[ni]));
        }
      }
  } else {
    const float* be = bias + (size_t)e * HDIM;
    float bv[4];
#pragma unroll
    for (int ni = 0; ni < 4; ++ni) bv[ni] = be[nt * 256 + wn * 64 + ni * 16 + l15];
#pragma unroll
    for (int mi = 0; mi < 8; ++mi)
#pragma unroll
      for (int rr = 0; rr < 4; ++rr) {
        int row = mt * 256 + wm * 128 + (mi >> 2) * 64 + (mi & 3) * 16 + (lane >> 4) * 4 + rr;
        if (row < ne) {
          int p = pb + row;
          int ts = pair_tok[p];        // (tok<<1)|slot in [0,16384)
          float w = pair_w[p];
          float* sr = stage + (size_t)ts * HDIM + nt * 256 + wn * 64 + l15;
#pragma unroll
          for (int ni = 0; ni < 4; ++ni)
            sr[ni * 16] = (acc[(mi >> 2) * 4 + (mi & 3)][ni][rr] + bv[ni]) * w;
        }
      }
  }
}

// ---------------- combine: out[t] = stage[2t] + stage[2t+1] ----------------
__global__ __launch_bounds__(256) void combine_kernel(const float* __restrict__ stage,
                                                      float* __restrict__ out) {
  const int n4 = T_TOK * HDIM / 4;
  int i = blockIdx.x * 256 + threadIdx.x;
  int stride = gridDim.x * 256;
  const float4* s = (const float4*)stage;
  float4* o = (float4*)out;
  for (; i < n4; i += stride) {
    int t = i / (HDIM / 4);
    int h = i - t * (HDIM / 4);
    float4 a = s[(size_t)t * (HDIM / 2) + h];
    float4 b = s[(size_t)t * (HDIM / 2) + (HDIM / 4) + h];
    float4 rr; rr.x = a.x + b.x; rr.y = a.y + b.y; rr.z = a.z + b.z; rr.w = a.w + b.w;
    o[i] = rr;
  }
}

extern "C" void kernel_launch(void* const* d_in, const int* in_sizes, int n_in,
                              void* d_out, int out_size, void* d_ws, size_t ws_size,
                              hipStream_t stream) {
  const float* x  = (const float*)d_in[0];
  const float* Wr = (const float*)d_in[1];
  const float* Wi = (const float*)d_in[2];
  const float* bi = (const float*)d_in[3];
  const float* Wo = (const float*)d_in[4];
  const float* bo = (const float*)d_in[5];
  float* out = (float*)d_out;
  char* ws = (char*)d_ws;

  unsigned short* xb   = (unsigned short*)(ws + OFF_XB);
  unsigned short* wib  = (unsigned short*)(ws + OFF_WIB);
  unsigned short* wob  = (unsigned short*)(ws + OFF_WOB);
  unsigned short* hbuf = (unsigned short*)(ws + OFF_HBUF);
  int*   counts   = (int*)(ws + OFF_META);
  int*   basep    = (int*)(ws + OFF_META + 64);
  int*   cursor   = (int*)(ws + OFF_META + 128);
  int*   tok_e    = (int*)(ws + OFF_TOKE);
  float* tok_w    = (float*)(ws + OFF_TOKW);
  int*   pair_tok = (int*)(ws + OFF_PTOK);
  float* pair_w   = (float*)(ws + OFF_PW);
  int*   tile_e   = (int*)(ws + OFF_TILE);
  int*   tile_mt  = (int*)(ws + OFF_TILE + 512);
  int*   ntiles   = (int*)(ws + OFF_TILE + 1024);
  float* stage    = (float*)(ws + OFF_STAGE);

  hipFuncSetAttribute((const void*)&moe_gemm<0>,
                      hipFuncAttributeMaxDynamicSharedMemorySize, 65536);
  hipFuncSetAttribute((const void*)&moe_gemm<1>,
                      hipFuncAttributeMaxDynamicSharedMemorySize, 65536);

  hipMemsetAsync(ws + OFF_META, 0, 256, stream);

  router_kernel<<<T_TOK / 4, 256, 0, stream>>>(x, Wr, tok_e, tok_w, xb);
  cvt_kernel<<<2048, 256, 0, stream>>>(Wi, wib, NEXP * FDIM * HDIM / 4);
  cvt_kernel<<<2048, 256, 0, stream>>>(Wo, wob, NEXP * HDIM * FDIM / 4);

  count_kernel<<<64, 256, 0, stream>>>(tok_e, counts);
  scan_build_kernel<<<1, 64, 0, stream>>>(counts, basep, tile_e, tile_mt, ntiles);
  scatter_kernel<<<64, 256, 0, stream>>>(tok_e, tok_w, basep, cursor, pair_tok, pair_w);

  // grids: 8 XCDs x 9 mt-slots x NTC; nt-major/mt-inner decode inside (R8 best)
  // 64 KB LDS -> 2 blocks/CU co-resident
  moe_gemm<0><<<8 * 9 * (FDIM / 256), 512, 65536, stream>>>(
      xb, wib, bi, counts, basep, pair_tok, pair_w, tile_e, tile_mt, ntiles, hbuf, nullptr);
  moe_gemm<1><<<8 * 9 * (HDIM / 256), 512, 65536, stream>>>(
      hbuf, wob, bo, counts, basep, pair_tok, pair_w, tile_e, tile_mt, ntiles, nullptr, stage);

  combine_kernel<<<2048, 256, 0, stream>>>(stage, out);
}